// Round 6
// baseline (227.299 us; speedup 1.0000x reference)
//
#include <hip/hip_runtime.h>
#include <hip/hip_bf16.h>

// CenterLoss: loss = ( sum_i clamp(||x_i - c_{label_i}||^2, 1e-12, 1e12)
//                      + B*(C-1)*1e-12 ) / B
// R1: 110us main -- serialized same-address atomics. Envelope ~79us fixed
//     (256MB 0xAA ws-poison @ ~41us + d_in restores; harness-owned).
// R2-R5: two-kernel partials+reduce, kernel-side ~22-27us regardless of MLP
//     structure (simple loop == 2rows/wave == fully staged regs) => main is
//     near its ~9-15us floor; residual is the 2nd launch + serialized reduce.
// R6: fuse into ONE kernel: last-arriving block reduces the 2048 partials.
//     Cross-XCD safety (G16): partials via agent-scope __hip_atomic_* (bypass
//     non-coherent L1/L2 copies). Arrival counter exploits the documented
//     0xAA re-poison of d_ws: counter starts at 0xAAAAAAAA every call, so
//     last block sees old == 0xAAAAAAAA + NB-1. No init dispatch needed.

#define BATCH 8192
#define NUM_CLASSES 751
#define FEAT_DIM 2048
#define NB 2048          // 4 waves/block, 1 row/wave -> 8192 rows exact
#define POISON 0xAAAAAAAAu

__global__ __launch_bounds__(256) void center_loss_fused(
        const float* __restrict__ x,
        const int* __restrict__ labels,
        const float* __restrict__ centers,
        float* __restrict__ partial,
        unsigned int* __restrict__ counter,
        float* __restrict__ out) {
    const int t = threadIdx.x;
    const int wave = t >> 6;
    const int lane = t & 63;
    const int row = blockIdx.x * 4 + wave;
    const int lab = labels[row];

    const float4* __restrict__ xr = (const float4*)(x + (size_t)row * FEAT_DIM);
    const float4* __restrict__ cr = (const float4*)(centers + (size_t)lab * FEAT_DIM);

    // 512 float4 per row / 64 lanes = 8 float4 per lane. (R2 structure --
    // measured best; staged-regs and 2-rows/wave variants were not faster.)
    float acc = 0.0f;
#pragma unroll
    for (int k = 0; k < 8; ++k) {
        const float4 xv = xr[lane + k * 64];
        const float4 cv = cr[lane + k * 64];
        float d;
        d = xv.x - cv.x; acc += d * d;
        d = xv.y - cv.y; acc += d * d;
        d = xv.z - cv.z; acc += d * d;
        d = xv.w - cv.w; acc += d * d;
    }

    // wave(64) shuffle reduction
#pragma unroll
    for (int off = 32; off > 0; off >>= 1)
        acc += __shfl_down(acc, off, 64);

    __shared__ float ws[4];
    __shared__ int is_last;
    if (lane == 0)
        ws[wave] = fminf(fmaxf(acc, 1e-12f), 1e12f);  // clamp is per-row
    __syncthreads();

    if (t == 0) {
        const float p = ws[0] + ws[1] + ws[2] + ws[3];
        // agent-scope store: lands at the coherent point, visible to any XCD
        __hip_atomic_store(&partial[blockIdx.x], p,
                           __ATOMIC_RELEASE, __HIP_MEMORY_SCOPE_AGENT);
        const unsigned int old = __hip_atomic_fetch_add(
                counter, 1u, __ATOMIC_ACQ_REL, __HIP_MEMORY_SCOPE_AGENT);
        is_last = (old == POISON + (NB - 1)) ? 1 : 0;
    }
    __syncthreads();   // broadcast is_last (block-uniform from here)

    if (is_last) {
        float s = 0.0f;
#pragma unroll
        for (int i = 0; i < NB / 256; ++i)
            s += __hip_atomic_load(&partial[t + i * 256],
                                   __ATOMIC_RELAXED, __HIP_MEMORY_SCOPE_AGENT);
#pragma unroll
        for (int off = 32; off > 0; off >>= 1)
            s += __shfl_down(s, off, 64);

        if (lane == 0) ws[wave] = s;
        __syncthreads();
        if (t == 0) {
            // masked-out zeros -> clamp 1e-12: B*(C-1)*1e-12 total, /B -> 7.5e-10
            out[0] = (ws[0] + ws[1] + ws[2] + ws[3]) * (1.0f / BATCH) + 7.5e-10f;
        }
    }
}

extern "C" void kernel_launch(void* const* d_in, const int* in_sizes, int n_in,
                              void* d_out, int out_size, void* d_ws, size_t ws_size,
                              hipStream_t stream) {
    const float* x = (const float*)d_in[0];
    const int* labels = (const int*)d_in[1];
    const float* centers = (const float*)d_in[2];
    float* out = (float*)d_out;

    unsigned int* counter = (unsigned int*)d_ws;          // starts 0xAAAAAAAA (poison)
    float* partial = (float*)((char*)d_ws + 1024);        // own cachelines; NB floats

    center_loss_fused<<<NB, 256, 0, stream>>>(x, labels, centers,
                                              partial, counter, out);
}

// Round 7
// 102.374 us; speedup vs baseline: 2.2203x; 2.2203x over previous
//
#include <hip/hip_runtime.h>
#include <hip/hip_bf16.h>

// CenterLoss: loss = ( sum_i clamp(||x_i - c_{label_i}||^2, 1e-12, 1e12)
//                      + B*(C-1)*1e-12 ) / B
// R1: 110us -- serialized same-address atomics.
// R2: two-kernel partials+reduce -> 101.3us total (BEST). ~79us is fixed
//     harness envelope (256MB 0xAA ws-poison + d_in restores); kernel-side
//     ~22us vs ~9-10us HBM floor + ~4-6us launch/ramp.
// R3 (2 rows/wave), R5 (staged regs + nontemporal): neutral -- main loop is
//     already latency-hidden; body shape doesn't matter.
// R6 (fused, last-block reduce w/ agent-scope atomics): 2x REGRESSION --
//     per-block agent-scope release/acquire fences (L2 writeback+invalidate)
//     collapsed streaming BW to ~350 GB/s. Fusion via coherent atomics is a
//     net loss on non-coherent-XCD hardware. Reverted to R2.

#define BATCH 8192
#define NUM_CLASSES 751
#define FEAT_DIM 2048
#define NB 1024          // blocks; 4 waves/block x 2 rows/wave -> 8192 rows

__global__ __launch_bounds__(256) void center_loss_main(
        const float* __restrict__ x,
        const int* __restrict__ labels,
        const float* __restrict__ centers,
        float* __restrict__ partial) {
    const int t = threadIdx.x;
    const int wave = t >> 6;
    const int lane = t & 63;
    const int r0 = blockIdx.x * 8 + wave * 2;   // rows r0, r0+1

    const int lab0 = labels[r0];
    const int lab1 = labels[r0 + 1];

    const float4* __restrict__ x0 = (const float4*)(x + (size_t)r0 * FEAT_DIM);
    const float4* __restrict__ x1 = (const float4*)(x + (size_t)(r0 + 1) * FEAT_DIM);
    const float4* __restrict__ c0 = (const float4*)(centers + (size_t)lab0 * FEAT_DIM);
    const float4* __restrict__ c1 = (const float4*)(centers + (size_t)lab1 * FEAT_DIM);

    // 512 float4 per row / 64 lanes = 8 float4 per lane per row.
    float acc0 = 0.0f, acc1 = 0.0f;
#pragma unroll
    for (int k = 0; k < 8; ++k) {
        const float4 xa = x0[lane + k * 64];
        const float4 ca = c0[lane + k * 64];
        const float4 xb = x1[lane + k * 64];
        const float4 cb = c1[lane + k * 64];
        float d;
        d = xa.x - ca.x; acc0 += d * d;
        d = xa.y - ca.y; acc0 += d * d;
        d = xa.z - ca.z; acc0 += d * d;
        d = xa.w - ca.w; acc0 += d * d;
        d = xb.x - cb.x; acc1 += d * d;
        d = xb.y - cb.y; acc1 += d * d;
        d = xb.z - cb.z; acc1 += d * d;
        d = xb.w - cb.w; acc1 += d * d;
    }

    // wave(64) shuffle reductions
#pragma unroll
    for (int off = 32; off > 0; off >>= 1) {
        acc0 += __shfl_down(acc0, off, 64);
        acc1 += __shfl_down(acc1, off, 64);
    }

    if (lane == 0) {
        partial[r0]     = fminf(fmaxf(acc0, 1e-12f), 1e12f);
        partial[r0 + 1] = fminf(fmaxf(acc1, 1e-12f), 1e12f);
    }
}

__global__ __launch_bounds__(256) void center_loss_reduce(
        const float* __restrict__ partial,
        float* __restrict__ out) {
    const int t = threadIdx.x;
    float s = 0.0f;
#pragma unroll
    for (int i = 0; i < BATCH / 256; ++i)
        s += partial[t + i * 256];

#pragma unroll
    for (int off = 32; off > 0; off >>= 1)
        s += __shfl_down(s, off, 64);

    __shared__ float ws[4];
    if ((t & 63) == 0) ws[t >> 6] = s;
    __syncthreads();

    if (t == 0) {
        // masked-out zeros -> clamp to 1e-12: (C-1)*1e-12 per row, /B cancels B
        out[0] = (ws[0] + ws[1] + ws[2] + ws[3]) * (1.0f / BATCH) + 7.5e-10f;
    }
}

extern "C" void kernel_launch(void* const* d_in, const int* in_sizes, int n_in,
                              void* d_out, int out_size, void* d_ws, size_t ws_size,
                              hipStream_t stream) {
    const float* x = (const float*)d_in[0];
    const int* labels = (const int*)d_in[1];
    const float* centers = (const float*)d_in[2];
    float* out = (float*)d_out;
    float* partial = (float*)d_ws;   // BATCH floats = 32 KB scratch

    center_loss_main<<<NB, 256, 0, stream>>>(x, labels, centers, partial);
    center_loss_reduce<<<1, 256, 0, stream>>>(partial, out);
}